// Round 16
// baseline (468.546 us; speedup 1.0000x reference)
//
#include <hip/hip_runtime.h>

#define B_ 8192
#define T_ 36
#define F_ 36
#define N_ELEM (B_*T_*F_)   // 10616832
// fallback xh scratch (ushort) inside fe/fem out regions
#define XHF_OFF (N_ELEM + 4)
#define XHB_OFF (2*N_ELEM + 4)

typedef __attribute__((ext_vector_type(8))) short bf16x8;
typedef __attribute__((ext_vector_type(4))) float f32x4;

__device__ inline short f2bf(float x){
  union { float f; unsigned u; } v; v.f = x;
  unsigned r = v.u + 0x7FFFu + ((v.u >> 16) & 1u);
  return (short)(r >> 16);
}
__device__ inline float bf2f(unsigned short u){
  union { unsigned u32; float f; } v; v.u32 = ((unsigned)u) << 16; return v.f;
}
__device__ inline float sigm(float x){
  return __builtin_amdgcn_rcpf(1.f + __expf(-x));
}

// ws layout (bytes)
#define WS_WC   0         // bf16 [512][256]: cols 0..107=W_ih, 108=bias, 109..127=0, 128..255=W_hh
                          // rows pre-scaled: i,f,o x log2(e); g x 2*log2(e)  (exp2-folded gates)
#define WS_WH   262144    // bf16 [2][64][128]: W_hist per direction, rows 36..63 = 0
#define WS_WP   294912    // bf16 [48][128]:   W_wc padded (k 72..127 = 0)
#define WS_BIAS 307200    // f32 [512] (unused by lstm; layout stability)
#define WS_LACC 309248    // f32 [72][16]: num[t] at [t][0], den[t] at [36+t][0]
#define WS_XH   313856    // optional xh scratch: 2 x N_ELEM bf16 (fused path)

__global__ __launch_bounds__(256) void prep_kernel(
    const float* __restrict__ Wih, const float* __restrict__ Whh,
    const float* __restrict__ bih, const float* __restrict__ bhh,
    const float* __restrict__ Whist, const float* __restrict__ Wwc,
    char* __restrict__ ws)
{
  short* Wc   = (short*)(ws + WS_WC);
  short* Wh   = (short*)(ws + WS_WH);
  short* Wp   = (short*)(ws + WS_WP);
  float* bias = (float*)(ws + WS_BIAS);
  float* lacc = (float*)(ws + WS_LACC);
  int i = blockIdx.x*256 + threadIdx.x;
  if (i < 131072){
    int n = i >> 8, k = i & 255;
    float v = 0.f;
    if (k < 108) v = Wih[n*108 + k];
    else if (k == 108) v = bih[n] + bhh[n];      // bias rides the constant-1 input column
    else if (k >= 128) v = Whh[n*128 + (k - 128)];
    // exp2-fold: sigmoid gates (i,f,o) scaled by log2e; tanh gate (g) by 2*log2e
    float sc = (n >= 256 && n < 384) ? 2.8853900817779268f : 1.4426950408889634f;
    Wc[i] = f2bf(v * sc);
  }
  if (i < 16384){
    int d = i >> 13, f = (i >> 7) & 63, k = i & 127;
    Wh[i] = (f < 36) ? f2bf(Whist[f*256 + d*128 + k]) : (short)0;
  }
  if (i < 6144){
    int f = i >> 7, k = i & 127;
    Wp[i] = (f < 36 && k < 72) ? f2bf(Wwc[f*72 + k]) : (short)0;
  }
  if (i < 512) bias[i] = bih[i] + bhh[i];
  if (i < 1152) lacc[i] = 0.f;
}

// Persistent LSTM: block = 64 rows x 1 dir, 8 waves, grid 256 (single round, 1 block/CU).
// R13 skeleton + xhs stride 44 (bank-safe) + EMIT FUSED INTO GATE LOOP: the emit
// MFMA's A-fragment at kc' = kc-4 equals the gate loop's hb read at kc (same LDS
// address), so emit rides the gate loop for free at mt==emt — deletes 48 hb
// b128 re-reads/CU/step. t==35 keeps the standalone emit (gates skipped).
__global__ __launch_bounds__(512, 2) void lstm_kernel(
  const float* __restrict__ fv, const float* __restrict__ fm, const float* __restrict__ fd,
  const float* __restrict__ bv, const float* __restrict__ bm, const float* __restrict__ bd,
  const char* __restrict__ ws,
  unsigned short* __restrict__ xhgF, unsigned short* __restrict__ xhgB)
{
  int dir = blockIdx.x & 1, tile = blockIdx.x >> 1;
  int b0 = tile * 64;
  const float* V = dir ? bv : fv;
  const float* M = dir ? bm : fm;
  const float* D = dir ? bd : fd;
  const short* Wc = (const short*)(ws + WS_WC);
  const short* Wh = (const short*)(ws + WS_WH) + dir*8192;
  unsigned short* xhg = dir ? xhgB : xhgF;     // [t][b][f] bf16

  __shared__ short xch[5*8192];     // 5-slice ring [64][128] bf16, swizzled (80 KB)
  __shared__ short hb[2][8192];     // h double buffer [64][128] bf16, swizzled (32 KB)
  __shared__ float xhs[2][2816];    // xh slice dbuf [64][44] f32 (22 KB, bank-safe)
  __shared__ short whl[6144];       // W_hist (this dir) [48][128] bf16, swizzled (12 KB)

  int tid = threadIdx.x, w = tid >> 6, l = tid & 63;
  int lr = l & 15, lg = l >> 4;
  int j = w*16 + lr;
  // emit tiles: A = (emt=w&3, ent=w>>2) for all 8 waves; B = (emt=w, ent=2) for w<4
  int emtA = w & 3, entA = w >> 2;

  { // zero xch + hb (28672 ints)
    int* z = (int*)xch;
    #pragma unroll
    for (int i = 0; i < 40; ++i) z[tid + i*512] = 0;
    int* z2 = (int*)hb;
    #pragma unroll
    for (int i = 0; i < 16; ++i) z2[tid + i*512] = 0;
  }
  __syncthreads();
  // constant-1.0 column at k=108 in all 5 slices
  if (tid < 320) {
    int sl = tid >> 6, r = tid & 63;
    int off = ((r << 8) + (108 << 1)) ^ ((r & 7) << 4);
    *(short*)((char*)xch + sl*16384 + off) = (short)0x3F80;
  }
  // W_hist -> LDS (swizzled), 768 b128 items
  for (int i = tid; i < 768; i += 512) {
    int f = i >> 4, kg = i & 15;
    int off = (f*256 + kg*16) ^ ((f & 7) << 4);
    *(bf16x8*)((char*)whl + off) = *(const bf16x8*)(Wh + f*128 + kg*8);
  }

  // gate weights -> registers (once)
  bf16x8 wreg[8][4];
  #pragma unroll
  for (int kc = 0; kc < 8; ++kc)
    #pragma unroll
    for (int g = 0; g < 4; ++g)
      wreg[kc][g] = *(const bf16x8*)(Wc + (g*128 + j)*256 + kc*32 + lg*8);

  float c[4][4];
  #pragma unroll
  for (int a = 0; a < 4; ++a)
    #pragma unroll
    for (int b = 0; b < 4; ++b) c[a][b] = 0.f;

  // staging: chunk = 2 steps = 3 arrays x 64 rows x 18 q = 3456 f32x4 items
  f32x4 rg[7];
  const float* gp[7]; int tin7[7], soff7[7]; bool act7[7];
  #pragma unroll
  for (int k = 0; k < 7; ++k) {
    int i = tid + k*512;
    act7[k] = i < 3456;
    int ii = act7[k] ? i : 0;
    int a = ii / 1152, rem = ii - a*1152;
    int r = rem / 18, q = rem - r*18;
    int t_in = q / 9, fq = (q - t_in*9)*4;
    gp[k] = (a == 0 ? V : (a == 1 ? M : D)) + (size_t)(b0 + r)*1296 + t_in*36 + fq;
    tin7[k] = t_in;
    soff7[k] = ((r << 8) + ((a*36 + fq) << 1)) ^ ((r & 7) << 4);
  }
  auto load_chunk = [&](int ta) {
    #pragma unroll
    for (int k = 0; k < 7; ++k)
      if (act7[k]) rg[k] = __builtin_nontemporal_load((const f32x4*)(gp[k] + ta*36));
  };
  auto write_chunk = [&](int ta) {
    #pragma unroll
    for (int k = 0; k < 7; ++k)
      if (act7[k]) {
        int sl = ta + tin7[k]; sl -= (sl / 5) * 5;
        short4 s = { f2bf(rg[k][0]), f2bf(rg[k][1]), f2bf(rg[k][2]), f2bf(rg[k][3]) };
        *(short4*)((char*)xch + sl*16384 + soff7[k]) = s;
      }
  };

  // prologue: stage steps 0..3 into slices 0..3
  load_chunk(0); write_chunk(0);
  load_chunk(2); write_chunk(2);
  __syncthreads();

  auto do_emit = [&](int emt, int ent, int par, int cur) {
    f32x4 ea = {0.f, 0.f, 0.f, 0.f};
    int fr = ent*16 + lr;
    #pragma unroll
    for (int kc = 0; kc < 4; ++kc) {
      int r = emt*16 + lr, kk = kc*32 + lg*8;
      bf16x8 af  = *(bf16x8*)((char*)hb[cur] + (((r << 8) + (kk << 1)) ^ ((r & 7) << 4)));
      bf16x8 bfr = *(bf16x8*)((char*)whl + (((fr << 8) + (kk << 1)) ^ ((fr & 7) << 4)));
      ea = __builtin_amdgcn_mfma_f32_16x16x32_bf16(af, bfr, ea, 0, 0, 0);
    }
    if (fr < 36) {
      #pragma unroll
      for (int reg = 0; reg < 4; ++reg)
        xhs[par][(emt*16 + lg*4 + reg)*44 + fr] = ea[reg];
    }
  };

  int s5 = 0;                      // t % 5
  for (int t = 0; t < 36; ++t) {
    int cur = t & 1, nxt = cur ^ 1, par = t & 1;

    // store previous step's xh slice (bf16, coalesced; drains over this step)
    if (t > 0) {
      int tp = t - 1, pp = tp & 1;
      int tout = dir ? (35 - tp) : tp;
      for (int i = tid; i < 576; i += 512) {
        int r = i / 9, fq = (i - r*9)*4;
        f32x4 v = *(const f32x4*)&xhs[pp][r*44 + fq];
        ushort4 sv = { (unsigned short)f2bf(v[0]), (unsigned short)f2bf(v[1]),
                       (unsigned short)f2bf(v[2]), (unsigned short)f2bf(v[3]) };
        *(ushort4*)(xhg + ((size_t)tout*8192 + b0 + r)*36 + fq) = sv;
      }
    }

    // staging: loads at even t (chunk t+2), commit at odd t (steps t+1,t+2 -> slices %5)
    if (!(t & 1) && t >= 2 && t <= 32) load_chunk(t + 2);
    if ((t & 1) && t >= 3 && t <= 33) write_chunk(t + 1);

    if (t < 35) {
      // gates per M-tile (emit fused at kc>=4 when mt matches this wave's emit tile)
      #pragma unroll
      for (int mt = 0; mt < 4; ++mt) {
        f32x4 acc[4] = {{0.f,0.f,0.f,0.f},{0.f,0.f,0.f,0.f},
                        {0.f,0.f,0.f,0.f},{0.f,0.f,0.f,0.f}};
        f32x4 eaA = {0.f,0.f,0.f,0.f}, eaB = {0.f,0.f,0.f,0.f};
        bool doA = (mt == emtA);
        bool doB = (w < 4) && (mt == w);
        int frA = entA*16 + lr, frB = 32 + lr;
        #pragma unroll
        for (int kc = 0; kc < 8; ++kc) {
          const char* ub = (kc < 4) ? ((const char*)xch + s5*16384) : (const char*)hb[cur];
          int kk = (kc & 3)*32 + lg*8;
          int r = mt*16 + lr;
          bf16x8 af = *(bf16x8*)(ub + (((r << 8) + (kk << 1)) ^ ((r & 7) << 4)));
          #pragma unroll
          for (int g = 0; g < 4; ++g)
            acc[g] = __builtin_amdgcn_mfma_f32_16x16x32_bf16(af, wreg[kc][g], acc[g], 0, 0, 0);
          if (kc >= 4) {
            if (doA) {
              bf16x8 bA = *(bf16x8*)((char*)whl + (((frA << 8) + (kk << 1)) ^ ((frA & 7) << 4)));
              eaA = __builtin_amdgcn_mfma_f32_16x16x32_bf16(af, bA, eaA, 0, 0, 0);
            }
            if (doB) {
              bf16x8 bB = *(bf16x8*)((char*)whl + (((frB << 8) + (kk << 1)) ^ ((frB & 7) << 4)));
              eaB = __builtin_amdgcn_mfma_f32_16x16x32_bf16(af, bB, eaB, 0, 0, 0);
            }
          }
        }
        if (doA && frA < 36) {
          #pragma unroll
          for (int reg = 0; reg < 4; ++reg)
            xhs[par][(mt*16 + lg*4 + reg)*44 + frA] = eaA[reg];
        }
        if (doB && frB < 36) {
          #pragma unroll
          for (int reg = 0; reg < 4; ++reg)
            xhs[par][(mt*16 + lg*4 + reg)*44 + frB] = eaB[reg];
        }
        #pragma unroll
        for (int reg = 0; reg < 4; ++reg) {
          // logits pre-scaled: i,f,o by log2e; g by 2*log2e
          float ei = __builtin_amdgcn_exp2f(-acc[0][reg]);
          float ef = __builtin_amdgcn_exp2f(-acc[1][reg]);
          float ag = fminf(fmaxf(acc[2][reg], -43.3f), 43.3f);
          float eg = __builtin_amdgcn_exp2f(-ag);
          float eo = __builtin_amdgcn_exp2f(-acc[3][reg]);
          float fgate = __builtin_amdgcn_rcpf(1.f + ef);
          float ig = (1.f - eg) * __builtin_amdgcn_rcpf((1.f + ei) * (1.f + eg));
          float cc = fgate * c[mt][reg] + ig;
          c[mt][reg] = cc;
          float cs = fminf(fmaxf(cc, -15.f), 15.f);
          float ec = __builtin_amdgcn_exp2f(-2.8853900817779268f * cs);
          float h = (1.f - ec) * __builtin_amdgcn_rcpf((1.f + eo) * (1.f + ec));
          int rr = mt*16 + lg*4 + reg;
          *(short*)((char*)hb[nxt] + (((rr << 8) + (j << 1)) ^ ((rr & 7) << 4))) = f2bf(h);
        }
      }
    } else {
      // t == 35: emit-only (pre-update h of the last step)
      do_emit(emtA, entA, par, cur);
      if (w < 4) do_emit(w, 2, par, cur);
    }
    __syncthreads();
    s5 = (s5 == 4) ? 0 : s5 + 1;
  }

  // final slice t=35 (parity 1)
  {
    int tout = dir ? 0 : 35;
    for (int i = tid; i < 576; i += 512) {
      int r = i / 9, fq = (i - r*9)*4;
      f32x4 v = *(const f32x4*)&xhs[1][r*44 + fq];
      ushort4 sv = { (unsigned short)f2bf(v[0]), (unsigned short)f2bf(v[1]),
                     (unsigned short)f2bf(v[2]), (unsigned short)f2bf(v[3]) };
      *(ushort4*)(xhg + ((size_t)tout*8192 + b0 + r)*36 + fq) = sv;
    }
  }
}

// Finish (t-major): block = 64 consecutive b at one t. alpha via MFMA, x_c,
// masked-L1 partials. FUSE: also emits fe/fem copies (xh scratch lives in ws).
template<bool FUSE>
__global__ __launch_bounds__(256) void finish_kernel(
  const float* __restrict__ fv, const float* __restrict__ fm, const float* __restrict__ fd,
  const float* __restrict__ fe_in, const float* __restrict__ fem_in,
  const float* __restrict__ bwc, const float* __restrict__ bhist,
  const char* __restrict__ ws, float* __restrict__ out,
  const unsigned short* __restrict__ xhf, const unsigned short* __restrict__ xhb)
{
  const short* Wp = (const short*)(ws + WS_WP);
  float* lacc = (float*)(ws + WS_LACC);
  float* imp = out + 1;
  __shared__ short u2[8192];
  __shared__ float nacc, dacc;
  int tid = threadIdx.x, w = tid >> 6, l = tid & 63;
  int lr = l & 15, lg = l >> 4;
  int t = blockIdx.x >> 7;
  int b0 = (blockIdx.x & 127) * 64;

  if (tid == 0) { nacc = 0.f; dacc = 0.f; }

  for (int idx = tid; idx < 2048; idx += 256) {
    int r = idx >> 5, q = idx & 31;
    short4 s4 = {0, 0, 0, 0};
    if (q < 9) {
      f32x4 x4 = *(const f32x4*)(fm + ((size_t)(b0 + r)*36 + t)*36 + q*4);
      s4 = make_short4(f2bf(x4[0]), f2bf(x4[1]), f2bf(x4[2]), f2bf(x4[3]));
    } else if (q < 18) {
      f32x4 x4 = *(const f32x4*)(fd + ((size_t)(b0 + r)*36 + t)*36 + (q - 9)*4);
      s4 = make_short4(f2bf(x4[0]), f2bf(x4[1]), f2bf(x4[2]), f2bf(x4[3]));
    }
    int off = ((r << 8) + ((q*4) << 1)) ^ ((r & 7) << 4);
    *(short4*)((char*)u2 + off) = s4;
  }
  __syncthreads();

  f32x4 acc[3] = {};
  #pragma unroll
  for (int kc = 0; kc < 3; ++kc) {
    int r = w*16 + lr, k = kc*32 + lg*8;
    bf16x8 af = *(bf16x8*)((char*)u2 + (((r << 8) + (k << 1)) ^ ((r & 7) << 4)));
    #pragma unroll
    for (int nt = 0; nt < 3; ++nt) {
      int f = nt*16 + lr;
      bf16x8 bfr = *(const bf16x8*)(Wp + f*128 + kc*32 + lg*8);
      acc[nt] = __builtin_amdgcn_mfma_f32_16x16x32_bf16(af, bfr, acc[nt], 0, 0, 0);
    }
  }

  #pragma unroll
  for (int reg = 0; reg < 4; ++reg) {
    int rr = w*16 + lg*4 + reg;
    size_t b = b0 + rr;
    float ns = 0.f, ds = 0.f;
    #pragma unroll
    for (int nt = 0; nt < 3; ++nt) {
      int f = nt*16 + lr;
      if (f < 36) {
        size_t gi  = (b*36 + t)*36 + f;
        size_t gi2 = ((size_t)t*8192 + b)*36 + f;
        float alpha = sigm(acc[nt][reg] + bwc[f]);
        float xhv = bf2f(xhf[gi2]) + bf2f(xhb[gi2]) + bhist[f];
        float xc = alpha*xhv + 1.f - alpha;
        imp[gi] = xc;
        float mm = fm[gi];
        ns += fabsf(fv[gi] - xc) * mm;
        ds += mm;
      }
    }
    #pragma unroll
    for (int s = 1; s < 16; s <<= 1) { ns += __shfl_xor(ns, s); ds += __shfl_xor(ds, s); }
    if (lr == 0) { atomicAdd(&nacc, ns); atomicAdd(&dacc, ds); }
  }

  if (FUSE) {
    float* feo  = out + 1 + (size_t)N_ELEM;
    float* femo = out + 1 + 2*(size_t)N_ELEM;
    for (int idx = tid; idx < 576; idx += 256) {
      int r = idx / 9, fq = (idx - r*9)*4;
      size_t gi = (size_t)(b0 + r)*1296 + (size_t)t*36 + fq;
      *(f32x4*)(feo  + gi) = *(const f32x4*)(fe_in  + gi);
      *(f32x4*)(femo + gi) = *(const f32x4*)(fem_in + gi);
    }
  }

  __syncthreads();
  if (tid == 0) {
    atomicAdd(lacc + t*16, nacc);
    atomicAdd(lacc + (36 + t)*16, dacc);
  }
}

__global__ void loss_final_kernel(const char* __restrict__ ws, float* __restrict__ out){
  const float* lacc = (const float*)(ws + WS_LACC);
  int t = threadIdx.x;
  float v = 0.f;
  if (t < 36) v = lacc[t*16] / (lacc[(36 + t)*16] + 1e-5f);
  #pragma unroll
  for (int s = 1; s < 64; s <<= 1) v += __shfl_xor(v, s);
  if (t == 0) out[0] = 0.3f * v;
}

extern "C" void kernel_launch(void* const* d_in, const int* in_sizes, int n_in,
                              void* d_out, int out_size, void* d_ws, size_t ws_size,
                              hipStream_t stream)
{
  const float* fv    = (const float*)d_in[0];
  const float* fm    = (const float*)d_in[1];
  const float* fd    = (const float*)d_in[2];
  const float* fe    = (const float*)d_in[3];
  const float* fem   = (const float*)d_in[4];
  const float* bv    = (const float*)d_in[5];
  const float* bm    = (const float*)d_in[6];
  const float* bd    = (const float*)d_in[7];
  const float* Wih   = (const float*)d_in[8];
  const float* Whh   = (const float*)d_in[9];
  const float* bih   = (const float*)d_in[10];
  const float* bhh   = (const float*)d_in[11];
  const float* Whist = (const float*)d_in[12];
  const float* bhist = (const float*)d_in[13];
  const float* Wwc   = (const float*)d_in[14];
  const float* bwc   = (const float*)d_in[15];
  float* out = (float*)d_out;
  char* ws = (char*)d_ws;

  size_t need = (size_t)WS_XH + 2*(size_t)N_ELEM*2;
  bool fuse = ws_size >= need;
  unsigned short* xhf = fuse ? (unsigned short*)(ws + WS_XH)
                             : (unsigned short*)(out + XHF_OFF);
  unsigned short* xhb = fuse ? (unsigned short*)(ws + WS_XH) + (size_t)N_ELEM
                             : (unsigned short*)(out + XHB_OFF);

  prep_kernel<<<512, 256, 0, stream>>>(Wih, Whh, bih, bhh, Whist, Wwc, ws);
  lstm_kernel<<<256, 512, 0, stream>>>(fv, fm, fd, bv, bm, bd, ws, xhf, xhb);
  if (fuse) {
    finish_kernel<true><<<4608, 256, 0, stream>>>(fv, fm, fd, fe, fem, bwc, bhist, ws, out, xhf, xhb);
  } else {
    finish_kernel<false><<<4608, 256, 0, stream>>>(fv, fm, fd, fe, fem, bwc, bhist, ws, out, xhf, xhb);
    hipMemcpyAsync(out + 1 + (size_t)N_ELEM, fe,  (size_t)N_ELEM*4, hipMemcpyDeviceToDevice, stream);
    hipMemcpyAsync(out + 1 + 2*(size_t)N_ELEM, fem, (size_t)N_ELEM*4, hipMemcpyDeviceToDevice, stream);
  }
  loss_final_kernel<<<1, 64, 0, stream>>>(ws, out);
}

// Round 17
// 386.590 us; speedup vs baseline: 1.2120x; 1.2120x over previous
//
#include <hip/hip_runtime.h>

#define B_ 8192
#define T_ 36
#define F_ 36
#define N_ELEM (B_*T_*F_)   // 10616832
// fallback xh scratch (ushort) inside fe/fem out regions
#define XHF_OFF (N_ELEM + 4)
#define XHB_OFF (2*N_ELEM + 4)

typedef __attribute__((ext_vector_type(8))) short bf16x8;
typedef __attribute__((ext_vector_type(4))) float f32x4;

__device__ inline short f2bf(float x){
  union { float f; unsigned u; } v; v.f = x;
  unsigned r = v.u + 0x7FFFu + ((v.u >> 16) & 1u);
  return (short)(r >> 16);
}
__device__ inline float bf2f(unsigned short u){
  union { unsigned u32; float f; } v; v.u32 = ((unsigned)u) << 16; return v.f;
}
__device__ inline float sigm(float x){
  return __builtin_amdgcn_rcpf(1.f + __expf(-x));
}

// ws layout (bytes)
#define WS_WC   0         // bf16 [512][256]: cols 0..107=W_ih, 108=bias, 109..127=0, 128..255=W_hh
                          // rows pre-scaled: i,f,o x log2(e); g x 2*log2(e)  (exp2-folded gates)
#define WS_WH   262144    // bf16 [2][64][128]: W_hist per direction, rows 36..63 = 0
#define WS_WP   294912    // bf16 [48][128]:   W_wc padded (k 72..127 = 0)
#define WS_BIAS 307200    // f32 [512] (unused by lstm; layout stability)
#define WS_LACC 309248    // f32 [72][16]: num[t] at [t][0], den[t] at [36+t][0]
#define WS_XH   313856    // optional xh scratch: 2 x N_ELEM bf16 (fused path)

__global__ __launch_bounds__(256) void prep_kernel(
    const float* __restrict__ Wih, const float* __restrict__ Whh,
    const float* __restrict__ bih, const float* __restrict__ bhh,
    const float* __restrict__ Whist, const float* __restrict__ Wwc,
    char* __restrict__ ws)
{
  short* Wc   = (short*)(ws + WS_WC);
  short* Wh   = (short*)(ws + WS_WH);
  short* Wp   = (short*)(ws + WS_WP);
  float* bias = (float*)(ws + WS_BIAS);
  float* lacc = (float*)(ws + WS_LACC);
  int i = blockIdx.x*256 + threadIdx.x;
  if (i < 131072){
    int n = i >> 8, k = i & 255;
    float v = 0.f;
    if (k < 108) v = Wih[n*108 + k];
    else if (k == 108) v = bih[n] + bhh[n];      // bias rides the constant-1 input column
    else if (k >= 128) v = Whh[n*128 + (k - 128)];
    // exp2-fold: sigmoid gates (i,f,o) scaled by log2e; tanh gate (g) by 2*log2e
    float sc = (n >= 256 && n < 384) ? 2.8853900817779268f : 1.4426950408889634f;
    Wc[i] = f2bf(v * sc);
  }
  if (i < 16384){
    int d = i >> 13, f = (i >> 7) & 63, k = i & 127;
    Wh[i] = (f < 36) ? f2bf(Whist[f*256 + d*128 + k]) : (short)0;
  }
  if (i < 6144){
    int f = i >> 7, k = i & 127;
    Wp[i] = (f < 36 && k < 72) ? f2bf(Wwc[f*72 + k]) : (short)0;
  }
  if (i < 512) bias[i] = bih[i] + bhh[i];
  if (i < 1152) lacc[i] = 0.f;
}

// Persistent LSTM: block = 64 rows x 1 dir, 8 waves, grid 256 (SINGLE round, 1 block/CU).
// Wave owns 16 gate cols x 4 gates (wreg: 128 regs). Per-mt split gates (4 M-tiles
// sequentially, acc 16 transient regs). Emit weights in LDS (whl), standalone emit
// phase (fusing it spills — R16). 5-slice x ring, chunk=2 staging. xhs stride 44
// (bank-safe). Per-step coalesced bf16 xh burst. 1 barrier/step.
__global__ __launch_bounds__(512, 2) void lstm_kernel(
  const float* __restrict__ fv, const float* __restrict__ fm, const float* __restrict__ fd,
  const float* __restrict__ bv, const float* __restrict__ bm, const float* __restrict__ bd,
  const char* __restrict__ ws,
  unsigned short* __restrict__ xhgF, unsigned short* __restrict__ xhgB)
{
  int dir = blockIdx.x & 1, tile = blockIdx.x >> 1;
  int b0 = tile * 64;
  const float* V = dir ? bv : fv;
  const float* M = dir ? bm : fm;
  const float* D = dir ? bd : fd;
  const short* Wc = (const short*)(ws + WS_WC);
  const short* Wh = (const short*)(ws + WS_WH) + dir*8192;
  unsigned short* xhg = dir ? xhgB : xhgF;     // [t][b][f] bf16

  __shared__ short xch[5*8192];     // 5-slice ring [64][128] bf16, swizzled (80 KB)
  __shared__ short hb[2][8192];     // h double buffer [64][128] bf16, swizzled (32 KB)
  __shared__ float xhs[2][2816];    // xh slice dbuf [64][44] f32 (22 KB, bank-safe)
  __shared__ short whl[6144];       // W_hist (this dir) [48][128] bf16, swizzled (12 KB)

  int tid = threadIdx.x, w = tid >> 6, l = tid & 63;
  int lr = l & 15, lg = l >> 4;
  int j = w*16 + lr;
  // emit tiles: A = (emt=w&3, ent=w>>2) for all 8 waves; B = (emt=w, ent=2) for w<4
  int emtA = w & 3, entA = w >> 2;

  { // zero xch + hb (28672 ints)
    int* z = (int*)xch;
    #pragma unroll
    for (int i = 0; i < 40; ++i) z[tid + i*512] = 0;
    int* z2 = (int*)hb;
    #pragma unroll
    for (int i = 0; i < 16; ++i) z2[tid + i*512] = 0;
  }
  __syncthreads();
  // constant-1.0 column at k=108 in all 5 slices
  if (tid < 320) {
    int sl = tid >> 6, r = tid & 63;
    int off = ((r << 8) + (108 << 1)) ^ ((r & 7) << 4);
    *(short*)((char*)xch + sl*16384 + off) = (short)0x3F80;
  }
  // W_hist -> LDS (swizzled), 768 b128 items
  for (int i = tid; i < 768; i += 512) {
    int f = i >> 4, kg = i & 15;
    int off = (f*256 + kg*16) ^ ((f & 7) << 4);
    *(bf16x8*)((char*)whl + off) = *(const bf16x8*)(Wh + f*128 + kg*8);
  }

  // gate weights -> registers (once)
  bf16x8 wreg[8][4];
  #pragma unroll
  for (int kc = 0; kc < 8; ++kc)
    #pragma unroll
    for (int g = 0; g < 4; ++g)
      wreg[kc][g] = *(const bf16x8*)(Wc + (g*128 + j)*256 + kc*32 + lg*8);

  float c[4][4];
  #pragma unroll
  for (int a = 0; a < 4; ++a)
    #pragma unroll
    for (int b = 0; b < 4; ++b) c[a][b] = 0.f;

  // staging: chunk = 2 steps = 3 arrays x 64 rows x 18 q = 3456 f32x4 items
  f32x4 rg[7];
  const float* gp[7]; int tin7[7], soff7[7]; bool act7[7];
  #pragma unroll
  for (int k = 0; k < 7; ++k) {
    int i = tid + k*512;
    act7[k] = i < 3456;
    int ii = act7[k] ? i : 0;
    int a = ii / 1152, rem = ii - a*1152;
    int r = rem / 18, q = rem - r*18;
    int t_in = q / 9, fq = (q - t_in*9)*4;
    gp[k] = (a == 0 ? V : (a == 1 ? M : D)) + (size_t)(b0 + r)*1296 + t_in*36 + fq;
    tin7[k] = t_in;
    soff7[k] = ((r << 8) + ((a*36 + fq) << 1)) ^ ((r & 7) << 4);
  }
  auto load_chunk = [&](int ta) {
    #pragma unroll
    for (int k = 0; k < 7; ++k)
      if (act7[k]) rg[k] = __builtin_nontemporal_load((const f32x4*)(gp[k] + ta*36));
  };
  auto write_chunk = [&](int ta) {
    #pragma unroll
    for (int k = 0; k < 7; ++k)
      if (act7[k]) {
        int sl = ta + tin7[k]; sl -= (sl / 5) * 5;
        short4 s = { f2bf(rg[k][0]), f2bf(rg[k][1]), f2bf(rg[k][2]), f2bf(rg[k][3]) };
        *(short4*)((char*)xch + sl*16384 + soff7[k]) = s;
      }
  };

  // prologue: stage steps 0..3 into slices 0..3
  load_chunk(0); write_chunk(0);
  load_chunk(2); write_chunk(2);
  __syncthreads();

  auto do_emit = [&](int emt, int ent, int par, int cur) {
    f32x4 ea = {0.f, 0.f, 0.f, 0.f};
    int fr = ent*16 + lr;
    #pragma unroll
    for (int kc = 0; kc < 4; ++kc) {
      int r = emt*16 + lr, kk = kc*32 + lg*8;
      bf16x8 af  = *(bf16x8*)((char*)hb[cur] + (((r << 8) + (kk << 1)) ^ ((r & 7) << 4)));
      bf16x8 bfr = *(bf16x8*)((char*)whl + (((fr << 8) + (kk << 1)) ^ ((fr & 7) << 4)));
      ea = __builtin_amdgcn_mfma_f32_16x16x32_bf16(af, bfr, ea, 0, 0, 0);
    }
    if (fr < 36) {
      #pragma unroll
      for (int reg = 0; reg < 4; ++reg)
        xhs[par][(emt*16 + lg*4 + reg)*44 + fr] = ea[reg];
    }
  };

  int s5 = 0;                      // t % 5
  for (int t = 0; t < 36; ++t) {
    int cur = t & 1, nxt = cur ^ 1, par = t & 1;

    // store previous step's xh slice (bf16, coalesced; drains over this step)
    if (t > 0) {
      int tp = t - 1, pp = tp & 1;
      int tout = dir ? (35 - tp) : tp;
      for (int i = tid; i < 576; i += 512) {
        int r = i / 9, fq = (i - r*9)*4;
        f32x4 v = *(const f32x4*)&xhs[pp][r*44 + fq];
        ushort4 sv = { (unsigned short)f2bf(v[0]), (unsigned short)f2bf(v[1]),
                       (unsigned short)f2bf(v[2]), (unsigned short)f2bf(v[3]) };
        *(ushort4*)(xhg + ((size_t)tout*8192 + b0 + r)*36 + fq) = sv;
      }
    }

    // staging: loads at even t (chunk t+2), commit at odd t (steps t+1,t+2 -> slices %5)
    if (!(t & 1) && t >= 2 && t <= 32) load_chunk(t + 2);
    if ((t & 1) && t >= 3 && t <= 33) write_chunk(t + 1);

    // emit xh_t = h_t @ W_hist^T (12 tiles over 8 waves)
    do_emit(emtA, entA, par, cur);
    if (w < 4) do_emit(w, 2, par, cur);

    if (t < 35) {
      // gates per M-tile: 32 MFMA + ew, acc transient
      #pragma unroll
      for (int mt = 0; mt < 4; ++mt) {
        f32x4 acc[4] = {{0.f,0.f,0.f,0.f},{0.f,0.f,0.f,0.f},
                        {0.f,0.f,0.f,0.f},{0.f,0.f,0.f,0.f}};
        #pragma unroll
        for (int kc = 0; kc < 8; ++kc) {
          const char* ub = (kc < 4) ? ((const char*)xch + s5*16384) : (const char*)hb[cur];
          int kk = (kc & 3)*32 + lg*8;
          int r = mt*16 + lr;
          bf16x8 af = *(bf16x8*)(ub + (((r << 8) + (kk << 1)) ^ ((r & 7) << 4)));
          #pragma unroll
          for (int g = 0; g < 4; ++g)
            acc[g] = __builtin_amdgcn_mfma_f32_16x16x32_bf16(af, wreg[kc][g], acc[g], 0, 0, 0);
        }
        #pragma unroll
        for (int reg = 0; reg < 4; ++reg) {
          // logits pre-scaled: i,f,o by log2e; g by 2*log2e
          float ei = __builtin_amdgcn_exp2f(-acc[0][reg]);
          float ef = __builtin_amdgcn_exp2f(-acc[1][reg]);
          float ag = fminf(fmaxf(acc[2][reg], -43.3f), 43.3f);
          float eg = __builtin_amdgcn_exp2f(-ag);
          float eo = __builtin_amdgcn_exp2f(-acc[3][reg]);
          float fgate = __builtin_amdgcn_rcpf(1.f + ef);
          float ig = (1.f - eg) * __builtin_amdgcn_rcpf((1.f + ei) * (1.f + eg));
          float cc = fgate * c[mt][reg] + ig;
          c[mt][reg] = cc;
          float cs = fminf(fmaxf(cc, -15.f), 15.f);
          float ec = __builtin_amdgcn_exp2f(-2.8853900817779268f * cs);
          float h = (1.f - ec) * __builtin_amdgcn_rcpf((1.f + eo) * (1.f + ec));
          int rr = mt*16 + lg*4 + reg;
          *(short*)((char*)hb[nxt] + (((rr << 8) + (j << 1)) ^ ((rr & 7) << 4))) = f2bf(h);
        }
      }
    }
    __syncthreads();
    s5 = (s5 == 4) ? 0 : s5 + 1;
  }

  // final slice t=35 (parity 1)
  {
    int tout = dir ? 0 : 35;
    for (int i = tid; i < 576; i += 512) {
      int r = i / 9, fq = (i - r*9)*4;
      f32x4 v = *(const f32x4*)&xhs[1][r*44 + fq];
      ushort4 sv = { (unsigned short)f2bf(v[0]), (unsigned short)f2bf(v[1]),
                     (unsigned short)f2bf(v[2]), (unsigned short)f2bf(v[3]) };
      *(ushort4*)(xhg + ((size_t)tout*8192 + b0 + r)*36 + fq) = sv;
    }
  }
}

// Finish (t-major): block = 64 consecutive b at one t. alpha via MFMA, x_c,
// masked-L1 partials. FUSE: also emits fe/fem copies (xh scratch lives in ws).
template<bool FUSE>
__global__ __launch_bounds__(256) void finish_kernel(
  const float* __restrict__ fv, const float* __restrict__ fm, const float* __restrict__ fd,
  const float* __restrict__ fe_in, const float* __restrict__ fem_in,
  const float* __restrict__ bwc, const float* __restrict__ bhist,
  const char* __restrict__ ws, float* __restrict__ out,
  const unsigned short* __restrict__ xhf, const unsigned short* __restrict__ xhb)
{
  const short* Wp = (const short*)(ws + WS_WP);
  float* lacc = (float*)(ws + WS_LACC);
  float* imp = out + 1;
  __shared__ short u2[8192];
  __shared__ float nacc, dacc;
  int tid = threadIdx.x, w = tid >> 6, l = tid & 63;
  int lr = l & 15, lg = l >> 4;
  int t = blockIdx.x >> 7;
  int b0 = (blockIdx.x & 127) * 64;

  if (tid == 0) { nacc = 0.f; dacc = 0.f; }

  for (int idx = tid; idx < 2048; idx += 256) {
    int r = idx >> 5, q = idx & 31;
    short4 s4 = {0, 0, 0, 0};
    if (q < 9) {
      f32x4 x4 = *(const f32x4*)(fm + ((size_t)(b0 + r)*36 + t)*36 + q*4);
      s4 = make_short4(f2bf(x4[0]), f2bf(x4[1]), f2bf(x4[2]), f2bf(x4[3]));
    } else if (q < 18) {
      f32x4 x4 = *(const f32x4*)(fd + ((size_t)(b0 + r)*36 + t)*36 + (q - 9)*4);
      s4 = make_short4(f2bf(x4[0]), f2bf(x4[1]), f2bf(x4[2]), f2bf(x4[3]));
    }
    int off = ((r << 8) + ((q*4) << 1)) ^ ((r & 7) << 4);
    *(short4*)((char*)u2 + off) = s4;
  }
  __syncthreads();

  f32x4 acc[3] = {};
  #pragma unroll
  for (int kc = 0; kc < 3; ++kc) {
    int r = w*16 + lr, k = kc*32 + lg*8;
    bf16x8 af = *(bf16x8*)((char*)u2 + (((r << 8) + (k << 1)) ^ ((r & 7) << 4)));
    #pragma unroll
    for (int nt = 0; nt < 3; ++nt) {
      int f = nt*16 + lr;
      bf16x8 bfr = *(const bf16x8*)(Wp + f*128 + kc*32 + lg*8);
      acc[nt] = __builtin_amdgcn_mfma_f32_16x16x32_bf16(af, bfr, acc[nt], 0, 0, 0);
    }
  }

  #pragma unroll
  for (int reg = 0; reg < 4; ++reg) {
    int rr = w*16 + lg*4 + reg;
    size_t b = b0 + rr;
    float ns = 0.f, ds = 0.f;
    #pragma unroll
    for (int nt = 0; nt < 3; ++nt) {
      int f = nt*16 + lr;
      if (f < 36) {
        size_t gi  = (b*36 + t)*36 + f;
        size_t gi2 = ((size_t)t*8192 + b)*36 + f;
        float alpha = sigm(acc[nt][reg] + bwc[f]);
        float xhv = bf2f(xhf[gi2]) + bf2f(xhb[gi2]) + bhist[f];
        float xc = alpha*xhv + 1.f - alpha;
        imp[gi] = xc;
        float mm = fm[gi];
        ns += fabsf(fv[gi] - xc) * mm;
        ds += mm;
      }
    }
    #pragma unroll
    for (int s = 1; s < 16; s <<= 1) { ns += __shfl_xor(ns, s); ds += __shfl_xor(ds, s); }
    if (lr == 0) { atomicAdd(&nacc, ns); atomicAdd(&dacc, ds); }
  }

  if (FUSE) {
    float* feo  = out + 1 + (size_t)N_ELEM;
    float* femo = out + 1 + 2*(size_t)N_ELEM;
    for (int idx = tid; idx < 576; idx += 256) {
      int r = idx / 9, fq = (idx - r*9)*4;
      size_t gi = (size_t)(b0 + r)*1296 + (size_t)t*36 + fq;
      *(f32x4*)(feo  + gi) = *(const f32x4*)(fe_in  + gi);
      *(f32x4*)(femo + gi) = *(const f32x4*)(fem_in + gi);
    }
  }

  __syncthreads();
  if (tid == 0) {
    atomicAdd(lacc + t*16, nacc);
    atomicAdd(lacc + (36 + t)*16, dacc);
  }
}

__global__ void loss_final_kernel(const char* __restrict__ ws, float* __restrict__ out){
  const float* lacc = (const float*)(ws + WS_LACC);
  int t = threadIdx.x;
  float v = 0.f;
  if (t < 36) v = lacc[t*16] / (lacc[(36 + t)*16] + 1e-5f);
  #pragma unroll
  for (int s = 1; s < 64; s <<= 1) v += __shfl_xor(v, s);
  if (t == 0) out[0] = 0.3f * v;
}

extern "C" void kernel_launch(void* const* d_in, const int* in_sizes, int n_in,
                              void* d_out, int out_size, void* d_ws, size_t ws_size,
                              hipStream_t stream)
{
  const float* fv    = (const float*)d_in[0];
  const float* fm    = (const float*)d_in[1];
  const float* fd    = (const float*)d_in[2];
  const float* fe    = (const float*)d_in[3];
  const float* fem   = (const float*)d_in[4];
  const float* bv    = (const float*)d_in[5];
  const float* bm    = (const float*)d_in[6];
  const float* bd    = (const float*)d_in[7];
  const float* Wih   = (const float*)d_in[8];
  const float* Whh   = (const float*)d_in[9];
  const float* bih   = (const float*)d_in[10];
  const float* bhh   = (const float*)d_in[11];
  const float* Whist = (const float*)d_in[12];
  const float* bhist = (const float*)d_in[13];
  const float* Wwc   = (const float*)d_in[14];
  const float* bwc   = (const float*)d_in[15];
  float* out = (float*)d_out;
  char* ws = (char*)d_ws;

  size_t need = (size_t)WS_XH + 2*(size_t)N_ELEM*2;
  bool fuse = ws_size >= need;
  unsigned short* xhf = fuse ? (unsigned short*)(ws + WS_XH)
                             : (unsigned short*)(out + XHF_OFF);
  unsigned short* xhb = fuse ? (unsigned short*)(ws + WS_XH) + (size_t)N_ELEM
                             : (unsigned short*)(out + XHB_OFF);

  prep_kernel<<<512, 256, 0, stream>>>(Wih, Whh, bih, bhh, Whist, Wwc, ws);
  lstm_kernel<<<256, 512, 0, stream>>>(fv, fm, fd, bv, bm, bd, ws, xhf, xhb);
  if (fuse) {
    finish_kernel<true><<<4608, 256, 0, stream>>>(fv, fm, fd, fe, fem, bwc, bhist, ws, out, xhf, xhb);
  } else {
    finish_kernel<false><<<4608, 256, 0, stream>>>(fv, fm, fd, fe, fem, bwc, bhist, ws, out, xhf, xhb);
    hipMemcpyAsync(out + 1 + (size_t)N_ELEM, fe,  (size_t)N_ELEM*4, hipMemcpyDeviceToDevice, stream);
    hipMemcpyAsync(out + 1 + 2*(size_t)N_ELEM, fem, (size_t)N_ELEM*4, hipMemcpyDeviceToDevice, stream);
  }
  loss_final_kernel<<<1, 64, 0, stream>>>(ws, out);
}